// Round 16
// baseline (525.035 us; speedup 1.0000x reference)
//
#include <hip/hip_runtime.h>

// WindowAttention3D: B=1024, N1=256, N2=128, C=128, NH=4, hd=32, nW=64
// out = [x (1024*256*128 f32)] ++ [attn (1024*4*256*128 f32)]
// R16: clean TLP x2 — 32-row tiles, 8192 blocks, LDS 34.8KB -> 4 blocks/CU
//      (16 waves/CU), natural VGPR (no min-wave launch bound), K/V loaded
//      per-qt from L1/L2 (raises MLP, frees registers). Window-major + NT.

typedef __attribute__((ext_vector_type(8))) short s16x8;
typedef __attribute__((ext_vector_type(4))) short s16x4;
typedef __attribute__((ext_vector_type(4))) float f32x4;

static __device__ __forceinline__ unsigned short f2bf(float f) {
  union { float f; unsigned u; } v; v.f = f;
  unsigned r = v.u + 0x7FFFu + ((v.u >> 16) & 1u);
  return (unsigned short)(r >> 16);
}

static __device__ __forceinline__ s16x8 cvt8(f32x4 a0, f32x4 a1) {
  s16x8 r;
  r[0] = (short)f2bf(a0[0]); r[1] = (short)f2bf(a0[1]);
  r[2] = (short)f2bf(a0[2]); r[3] = (short)f2bf(a0[3]);
  r[4] = (short)f2bf(a1[0]); r[5] = (short)f2bf(a1[1]);
  r[6] = (short)f2bf(a1[2]); r[7] = (short)f2bf(a1[3]);
  return r;
}

// ---------------- prep: weights->bf16, combined bias+mask table ----------------
// bm[w][h][q][n2] = rpb[rel_index[q][n2]][h] + mask[w][q][n2]   (f32, 32 MB)
__global__ void kw_prep(const float* __restrict__ qw, const float* __restrict__ kvw,
                        const float* __restrict__ pw, const float* __restrict__ rpb,
                        const int* __restrict__ relidx, const float* __restrict__ mask,
                        unsigned short* __restrict__ qwb, unsigned short* __restrict__ kvwb,
                        unsigned short* __restrict__ pwb, float* __restrict__ bm) {
  int tid = blockIdx.x * 256 + threadIdx.x;
  int stride = gridDim.x * 256;
  for (int i = tid; i < 65536; i += stride) {
    if (i < 16384)      qwb[i] = f2bf(qw[i]);
    else if (i < 49152) kvwb[i - 16384] = f2bf(kvw[i - 16384]);
    else                pwb[i - 49152] = f2bf(pw[i - 49152]);
  }
  for (int i = tid; i < 2097152; i += stride) {
    int wdw = i >> 15, j = i & 32767;
    int rel = relidx[j];
    float4 tv = *(const float4*)(rpb + rel * 4);
    float mk = mask[i];
    float* d = bm + (size_t)(wdw * 4) * 32768 + j;
    d[0]      = tv.x + mk;
    d[32768]  = tv.y + mk;
    d[65536]  = tv.z + mk;
    d[98304]  = tv.w + mk;
  }
}

// ---------------- kv projection: kws[b][h][n2][32], vT[b][h][dh][n2] ----------------
__global__ __launch_bounds__(256) void kkv(const float* __restrict__ kv,
    const unsigned short* __restrict__ kvwb, const float* __restrict__ kvb,
    unsigned short* __restrict__ kws, unsigned short* __restrict__ vT) {
  __shared__ unsigned short oK[64][136];
  __shared__ unsigned short oV[128][72];
  int b = blockIdx.x >> 1, r0 = (blockIdx.x & 1) << 6;
  int t = threadIdx.x;
  int w = t >> 6, l = t & 63, lm = l & 15, lg = l >> 4;
  const float* arow = kv + (size_t)(b * 128 + r0 + w * 16 + lm) * 128;
  f32x4 acc[16];
#pragma unroll
  for (int i = 0; i < 16; ++i) acc[i] = (f32x4){0.f, 0.f, 0.f, 0.f};
#pragma unroll
  for (int kk = 0; kk < 4; ++kk) {
    f32x4 a0 = __builtin_nontemporal_load((const f32x4*)(arow + kk * 32 + lg * 8));
    f32x4 a1 = __builtin_nontemporal_load((const f32x4*)(arow + kk * 32 + lg * 8 + 4));
    s16x8 a = cvt8(a0, a1);
#pragma unroll
    for (int ct = 0; ct < 16; ++ct) {
      s16x8 bf = *(const s16x8*)(kvwb + (ct * 16 + lm) * 128 + kk * 32 + lg * 8);
      acc[ct] = __builtin_amdgcn_mfma_f32_16x16x32_bf16(a, bf, acc[ct], 0, 0, 0);
    }
  }
#pragma unroll
  for (int ct = 0; ct < 16; ++ct) {
    int col = ct * 16 + lm;
    float bb = kvb[col];
    if (col < 128) {
#pragma unroll
      for (int r = 0; r < 4; ++r)
        oK[w * 16 + lg * 4 + r][col] = f2bf(acc[ct][r] + bb);
    } else {
      int d = col - 128;
      s16x4 pk;
#pragma unroll
      for (int r = 0; r < 4; ++r) pk[r] = (short)f2bf(acc[ct][r] + bb);
      *(s16x4*)&oV[d][w * 16 + lg * 4] = pk;
    }
  }
  __syncthreads();
  {
    int o = t * 8, row = o >> 5, cs = o & 31;
#pragma unroll
    for (int h = 0; h < 4; ++h) {
      s16x8 v = *(const s16x8*)&oK[row][h * 32 + cs];
      *(s16x8*)(kws + ((size_t)(b * 4 + h) * 128 + r0 + row) * 32 + cs) = v;
    }
  }
#pragma unroll
  for (int i = 0; i < 4; ++i) {
    int o = (t + i * 256) * 8;
    int d = o >> 6, ns = o & 63;
    s16x8 v = *(const s16x8*)&oV[d][ns];
    *(s16x8*)(vT + ((size_t)b * 128 + d) * 128 + r0 + ns) = v;
  }
}

// ---------------- fused: q-proj + attention + out-proj per (b, 32 q rows) ----------------
__global__ __launch_bounds__(256) void kfused(const float* __restrict__ q,
    const unsigned short* __restrict__ qwb, const float* __restrict__ qb,
    const unsigned short* __restrict__ kws, const unsigned short* __restrict__ vT,
    const float* __restrict__ bm, const unsigned short* __restrict__ pwb,
    const float* __restrict__ pb, float* __restrict__ attn_out,
    float* __restrict__ xout) {
  __shared__ unsigned short qhL[32][136];   // qh tile, all heads
  __shared__ unsigned short XL[32][136];    // attention output tile
  __shared__ float scratch[4][1088] __attribute__((aligned(16))); // per-wave [16][68]
  int bid = blockIdx.x;
  // window-major: the 8 q0-blocks of one (b) are adjacent -> K/V L1/L2-hot;
  // co-resident blocks share few bm windows.
  int wdw = bid >> 7, rr = bid & 127;
  int b = wdw + 64 * (rr >> 3);
  int q0 = (rr & 7) << 5;
  int t = threadIdx.x;
  int w = t >> 6, l = t & 63, lm = l & 15, lg = l >> 4;
  float* aSt = scratch[w];                  // [16][68] f32
  const f32x4 zero = {0.f, 0.f, 0.f, 0.f};

  // ---- Phase 1: q-proj; wave (wr=w&1, wc=w>>1): rows wr*16, cols wc*64 ----
  {
    int wr = w & 1, wc = w >> 1;
    const float* arow = q + (size_t)(b * 256 + q0 + wr * 16 + lm) * 128;
    f32x4 acc[4];
#pragma unroll
    for (int i = 0; i < 4; ++i) acc[i] = zero;
#pragma unroll
    for (int kk = 0; kk < 4; ++kk) {
      f32x4 a0 = __builtin_nontemporal_load((const f32x4*)(arow + kk * 32 + lg * 8));
      f32x4 a1 = __builtin_nontemporal_load((const f32x4*)(arow + kk * 32 + lg * 8 + 4));
      s16x8 a = cvt8(a0, a1);
#pragma unroll
      for (int ct = 0; ct < 4; ++ct) {
        s16x8 bf = *(const s16x8*)(qwb + (size_t)(wc * 64 + ct * 16 + lm) * 128 + kk * 32 + lg * 8);
        acc[ct] = __builtin_amdgcn_mfma_f32_16x16x32_bf16(a, bf, acc[ct], 0, 0, 0);
      }
    }
    const float SC = 0.17677669529663687f;   // 32^-0.5
#pragma unroll
    for (int ct = 0; ct < 4; ++ct) {
      int col = wc * 64 + ct * 16 + lm;
      float bb = qb[col];
#pragma unroll
      for (int r2 = 0; r2 < 4; ++r2)
        qhL[wr * 16 + lg * 4 + r2][col] = f2bf((acc[ct][r2] + bb) * SC);
    }
  }
  asm volatile("s_waitcnt lgkmcnt(0)" ::: "memory");
  __builtin_amdgcn_s_barrier();

  // ---- Phase 2: attention, wave w = head h, 2 subtiles of 16 q-rows ----
  {
    int h = w;
    const unsigned short* ksrc = kws + (size_t)(b * 4 + h) * 4096;
    const unsigned short* vsrc = vT + (size_t)(b * 4 + h) * 4096;
    const float* bmh = bm + (size_t)(wdw * 4 + h) * 32768;
    float* attnh = attn_out + ((size_t)(b * 4 + h) * 256 + q0) * 128;

#pragma unroll
    for (int qt = 0; qt < 2; ++qt) {
      int qg = q0 + qt * 16 + lm;
      s16x8 bq = *(const s16x8*)&qhL[qt * 16 + lm][h * 32 + lg * 8];
      f32x4 S[8];  // S^T: row n2 = ct*16+lg*4+r, col q = lm
#pragma unroll
      for (int ct = 0; ct < 8; ++ct) {
        // K fragment fresh from L1/L2 each qt (8 independent VMEM ops -> MLP)
        s16x8 ak = *(const s16x8*)(ksrc + (ct * 16 + lm) * 32 + lg * 8);
        S[ct] = __builtin_amdgcn_mfma_f32_16x16x32_bf16(ak, bq, zero, 0, 0, 0);
      }
      float m = -1e30f;
#pragma unroll
      for (int ct = 0; ct < 8; ++ct) {
        float4 bv = *(const float4*)(bmh + (size_t)qg * 128 + ct * 16 + lg * 4);
        S[ct][0] += bv.x; S[ct][1] += bv.y; S[ct][2] += bv.z; S[ct][3] += bv.w;
        m = fmaxf(m, fmaxf(fmaxf(S[ct][0], S[ct][1]), fmaxf(S[ct][2], S[ct][3])));
      }
      m = fmaxf(m, __shfl_xor(m, 16));
      m = fmaxf(m, __shfl_xor(m, 32));
      float s = 0.f;
#pragma unroll
      for (int ct = 0; ct < 8; ++ct) {
#pragma unroll
        for (int r2 = 0; r2 < 4; ++r2) { S[ct][r2] = __expf(S[ct][r2] - m); s += S[ct][r2]; }
      }
      s += __shfl_xor(s, 16);
      s += __shfl_xor(s, 32);
      float inv = 1.0f / s;
      float* adst = attnh + qt * 16 * 128;
      s16x8 pfrag[4];
#pragma unroll
      for (int ch = 0; ch < 2; ++ch) {
#pragma unroll
        for (int cc = 0; cc < 4; ++cc) {
          int ct = ch * 4 + cc;
          f32x4 pv = { S[ct][0] * inv, S[ct][1] * inv, S[ct][2] * inv, S[ct][3] * inv };
          *(f32x4*)(aSt + lm * 68 + cc * 16 + lg * 4) = pv;
        }
        // NT store: 16 rows x 256B (2 full 128B lines per segment)
#pragma unroll
        for (int i = 0; i < 4; ++i) {
          int o = l * 4 + i * 256;
          int row = o >> 6, col = o & 63;
          f32x4 v = *(const f32x4*)(aSt + row * 68 + col);
          __builtin_nontemporal_store(v, (f32x4*)(adst + row * 128 + ch * 64 + col));
        }
#pragma unroll
        for (int k2 = 0; k2 < 2; ++k2) {
          const float* pp = aSt + lm * 68 + k2 * 32 + lg * 8;
          pfrag[ch * 2 + k2] = cvt8(*(const f32x4*)pp, *(const f32x4*)(pp + 4));
        }
      }
      // PV: V fragments fresh from L1/L2 (8 independent VMEM ops)
      f32x4 O[2];
      O[0] = zero; O[1] = zero;
#pragma unroll
      for (int kk = 0; kk < 4; ++kk)
#pragma unroll
        for (int cd = 0; cd < 2; ++cd) {
          s16x8 av = *(const s16x8*)(vsrc + (cd * 16 + lm) * 128 + kk * 32 + lg * 8);
          O[cd] = __builtin_amdgcn_mfma_f32_16x16x32_bf16(av, pfrag[kk], O[cd], 0, 0, 0);
        }
#pragma unroll
      for (int cd = 0; cd < 2; ++cd) {
        s16x4 pk;
#pragma unroll
        for (int r2 = 0; r2 < 4; ++r2) pk[r2] = (short)f2bf(O[cd][r2]);
        *(s16x4*)&XL[qt * 16 + lm][h * 32 + cd * 16 + lg * 4] = pk;
      }
    }
  }
  asm volatile("s_waitcnt lgkmcnt(0)" ::: "memory");
  __builtin_amdgcn_s_barrier();   // attn NT stores keep draining under phase 3

  // ---- Phase 3: out-proj; wave (wr=w&1, wc=w>>1): rows wr*16, cols wc*64 ----
  {
    int wr = w & 1, wc = w >> 1;
    f32x4 acc[4];
#pragma unroll
    for (int i = 0; i < 4; ++i) acc[i] = zero;
#pragma unroll
    for (int kk = 0; kk < 4; ++kk) {
      s16x8 a = *(const s16x8*)&XL[wr * 16 + lm][kk * 32 + lg * 8];
#pragma unroll
      for (int ct = 0; ct < 4; ++ct) {
        s16x8 bf = *(const s16x8*)(pwb + (size_t)(wc * 64 + ct * 16 + lm) * 128 + kk * 32 + lg * 8);
        acc[ct] = __builtin_amdgcn_mfma_f32_16x16x32_bf16(a, bf, acc[ct], 0, 0, 0);
      }
    }
#pragma unroll
    for (int ct = 0; ct < 4; ++ct) {
      int col = wc * 64 + ct * 16 + lm;
      float bb = pb[col];
#pragma unroll
      for (int r2 = 0; r2 < 4; ++r2) acc[ct][r2] += bb;
    }
    // stage [16 rows][64 cols] f32, then 2-full-line NT stores
#pragma unroll
    for (int ct = 0; ct < 4; ++ct)
#pragma unroll
      for (int r2 = 0; r2 < 4; ++r2)
        aSt[(lg * 4 + r2) * 68 + ct * 16 + lm] = acc[ct][r2];
    float* xdst = xout + ((size_t)b * 256 + q0 + wr * 16) * 128;
#pragma unroll
    for (int i = 0; i < 4; ++i) {
      int o = l * 4 + i * 256;
      int row = o >> 6, col = o & 63;
      f32x4 v = *(const f32x4*)(aSt + row * 68 + col);
      __builtin_nontemporal_store(v, (f32x4*)(xdst + row * 128 + wc * 64 + col));
    }
  }
}

extern "C" void kernel_launch(void* const* d_in, const int* in_sizes, int n_in,
                              void* d_out, int out_size, void* d_ws, size_t ws_size,
                              hipStream_t stream) {
  const float* q    = (const float*)d_in[0];
  const float* kv   = (const float*)d_in[1];
  const float* mask = (const float*)d_in[2];
  const float* qw   = (const float*)d_in[3];
  const float* qb   = (const float*)d_in[4];
  const float* kvw  = (const float*)d_in[5];
  const float* kvb  = (const float*)d_in[6];
  const float* pw   = (const float*)d_in[7];
  const float* pb   = (const float*)d_in[8];
  const float* rpb  = (const float*)d_in[9];
  const int* relidx = (const int*)d_in[10];

  float* xout = (float*)d_out;
  float* attn = xout + (size_t)1024 * 256 * 128;   // 33,554,432

  char* ws = (char*)d_ws;
  unsigned short* qwb  = (unsigned short*)ws;                 // 32 KB
  unsigned short* kvwb = (unsigned short*)(ws + 32768);       // 64 KB
  unsigned short* pwb  = (unsigned short*)(ws + 98304);       // 32 KB
  float*          bm   = (float*)(ws + 131072);               // 32 MB
  unsigned short* kws  = (unsigned short*)(ws + 131072 + 33554432);  // 32 MB
  unsigned short* vT   = kws + (size_t)16777216;              // 32 MB

  kw_prep<<<2048, 256, 0, stream>>>(qw, kvw, pw, rpb, relidx, mask, qwb, kvwb, pwb, bm);
  kkv<<<2048, 256, 0, stream>>>(kv, kvwb, kvb, kws, vT);
  kfused<<<8192, 256, 0, stream>>>(q, qwb, qb, kws, vT, bm, pwb, pb, attn, xout);
}

// Round 17
// 339.280 us; speedup vs baseline: 1.5475x; 1.5475x over previous
//
#include <hip/hip_runtime.h>

// WindowAttention3D: B=1024, N1=256, N2=128, C=128, NH=4, hd=32, nW=64
// out = [x (1024*256*128 f32)] ++ [attn (1024*4*256*128 f32)]
// R17: MEGA-FUSION — one kernel per b: kv-proj (LDS-only K/V), q-proj,
//      attention, out-proj. kws/vT HBM round-trips deleted. K/V LDS space
//      overlaid by qh/X after K/V move to per-wave registers.

typedef __attribute__((ext_vector_type(8))) short s16x8;
typedef __attribute__((ext_vector_type(4))) short s16x4;
typedef __attribute__((ext_vector_type(4))) float f32x4;

static __device__ __forceinline__ unsigned short f2bf(float f) {
  union { float f; unsigned u; } v; v.f = f;
  unsigned r = v.u + 0x7FFFu + ((v.u >> 16) & 1u);
  return (unsigned short)(r >> 16);
}

static __device__ __forceinline__ s16x8 cvt8(f32x4 a0, f32x4 a1) {
  s16x8 r;
  r[0] = (short)f2bf(a0[0]); r[1] = (short)f2bf(a0[1]);
  r[2] = (short)f2bf(a0[2]); r[3] = (short)f2bf(a0[3]);
  r[4] = (short)f2bf(a1[0]); r[5] = (short)f2bf(a1[1]);
  r[6] = (short)f2bf(a1[2]); r[7] = (short)f2bf(a1[3]);
  return r;
}

// ---------------- prep: weights->bf16, combined bias+mask table ----------------
// bm[w][h][q][n2] = rpb[rel_index[q][n2]][h] + mask[w][q][n2]   (f32, 32 MB)
__global__ void kw_prep(const float* __restrict__ qw, const float* __restrict__ kvw,
                        const float* __restrict__ pw, const float* __restrict__ rpb,
                        const int* __restrict__ relidx, const float* __restrict__ mask,
                        unsigned short* __restrict__ qwb, unsigned short* __restrict__ kvwb,
                        unsigned short* __restrict__ pwb, float* __restrict__ bm) {
  int tid = blockIdx.x * 256 + threadIdx.x;
  int stride = gridDim.x * 256;
  for (int i = tid; i < 65536; i += stride) {
    if (i < 16384)      qwb[i] = f2bf(qw[i]);
    else if (i < 49152) kvwb[i - 16384] = f2bf(kvw[i - 16384]);
    else                pwb[i - 49152] = f2bf(pw[i - 49152]);
  }
  for (int i = tid; i < 2097152; i += stride) {
    int wdw = i >> 15, j = i & 32767;
    int rel = relidx[j];
    float4 tv = *(const float4*)(rpb + rel * 4);
    float mk = mask[i];
    float* d = bm + (size_t)(wdw * 4) * 32768 + j;
    d[0]      = tv.x + mk;
    d[32768]  = tv.y + mk;
    d[65536]  = tv.z + mk;
    d[98304]  = tv.w + mk;
  }
}

// ---------------- mega: kv-proj + q-proj + attention + out-proj per b ----------------
__global__ __launch_bounds__(512) void kmega(const float* __restrict__ q,
    const float* __restrict__ kv, const unsigned short* __restrict__ qwb,
    const float* __restrict__ qb, const unsigned short* __restrict__ kvwb,
    const float* __restrict__ kvb, const float* __restrict__ bm,
    const unsigned short* __restrict__ pwb, const float* __restrict__ pb,
    float* __restrict__ attn_out, float* __restrict__ xout) {
  __shared__ unsigned short big[256 * 136];   // kL[128][136]+vL[128][136] / qhL-X[256][136]
  __shared__ float scratch[8][1088] __attribute__((aligned(16))); // per-wave [16][68] f32
  unsigned short (*kL)[136]  = (unsigned short(*)[136])big;              // [128][136]
  unsigned short (*vL)[136]  = (unsigned short(*)[136])(big + 128 * 136);// [128][136]
  unsigned short (*qhL)[136] = (unsigned short(*)[136])big;              // [256][136] overlay

  int b = blockIdx.x;
  int wdw = b & 63;
  int t = threadIdx.x;
  int w = t >> 6, l = t & 63, lm = l & 15, lg = l >> 4;
  float* aSt = scratch[w];
  const f32x4 zero = {0.f, 0.f, 0.f, 0.f};

  // ---- Phase A: kv-proj into LDS; wave w -> kv rows w*16..+16, all 256 cols ----
  {
    const float* arow = kv + (size_t)(b * 128 + w * 16 + lm) * 128;
    f32x4 acc[16];
#pragma unroll
    for (int i = 0; i < 16; ++i) acc[i] = zero;
#pragma unroll
    for (int kk = 0; kk < 4; ++kk) {
      f32x4 a0 = __builtin_nontemporal_load((const f32x4*)(arow + kk * 32 + lg * 8));
      f32x4 a1 = __builtin_nontemporal_load((const f32x4*)(arow + kk * 32 + lg * 8 + 4));
      s16x8 a = cvt8(a0, a1);
#pragma unroll
      for (int ct = 0; ct < 16; ++ct) {
        s16x8 bf = *(const s16x8*)(kvwb + (ct * 16 + lm) * 128 + kk * 32 + lg * 8);
        acc[ct] = __builtin_amdgcn_mfma_f32_16x16x32_bf16(a, bf, acc[ct], 0, 0, 0);
      }
    }
#pragma unroll
    for (int ct = 0; ct < 16; ++ct) {
      int col = ct * 16 + lm;
      float bb = kvb[col];
      if (ct < 8) {               // K -> kL[n2][col]
#pragma unroll
        for (int r = 0; r < 4; ++r)
          kL[w * 16 + lg * 4 + r][col] = f2bf(acc[ct][r] + bb);
      } else {                    // V -> vL[d][n2] (transposed)
        int d = col - 128;
        s16x4 pk;
#pragma unroll
        for (int r = 0; r < 4; ++r) pk[r] = (short)f2bf(acc[ct][r] + bb);
        *(s16x4*)&vL[d][w * 16 + lg * 4] = pk;
      }
    }
  }
  asm volatile("s_waitcnt lgkmcnt(0)" ::: "memory");
  __builtin_amdgcn_s_barrier();

  // ---- Phase B: per-wave head K/V into registers (wave w: head h, q-half) ----
  int h = w & 3, rbase = (w >> 2) * 128;
  s16x8 ak[8], av[8];
#pragma unroll
  for (int ct = 0; ct < 8; ++ct)
    ak[ct] = *(const s16x8*)&kL[ct * 16 + lm][h * 32 + lg * 8];
#pragma unroll
  for (int kk = 0; kk < 4; ++kk)
#pragma unroll
    for (int cd = 0; cd < 2; ++cd)
      av[kk * 2 + cd] = *(const s16x8*)&vL[h * 32 + cd * 16 + lm][kk * 32 + lg * 8];
  asm volatile("s_waitcnt lgkmcnt(0)" ::: "memory");
  __builtin_amdgcn_s_barrier();   // K/V now in registers; LDS free for qh overlay

  // ---- Phase C: q-proj into qhL (overlay); wave w -> rows w*32..+32 ----
  {
    const float SC = 0.17677669529663687f;   // 32^-0.5
#pragma unroll
    for (int it = 0; it < 2; ++it) {
      int r0 = w * 32 + it * 16;
      const float* arow = q + (size_t)(b * 256 + r0 + lm) * 128;
      f32x4 acc[8];
#pragma unroll
      for (int i = 0; i < 8; ++i) acc[i] = zero;
#pragma unroll
      for (int kk = 0; kk < 4; ++kk) {
        f32x4 a0 = __builtin_nontemporal_load((const f32x4*)(arow + kk * 32 + lg * 8));
        f32x4 a1 = __builtin_nontemporal_load((const f32x4*)(arow + kk * 32 + lg * 8 + 4));
        s16x8 a = cvt8(a0, a1);
#pragma unroll
        for (int ct = 0; ct < 8; ++ct) {
          s16x8 bf = *(const s16x8*)(qwb + (ct * 16 + lm) * 128 + kk * 32 + lg * 8);
          acc[ct] = __builtin_amdgcn_mfma_f32_16x16x32_bf16(a, bf, acc[ct], 0, 0, 0);
        }
      }
#pragma unroll
      for (int ct = 0; ct < 8; ++ct) {
        int col = ct * 16 + lm;
        float bb = qb[col];
#pragma unroll
        for (int r2 = 0; r2 < 4; ++r2)
          qhL[r0 + lg * 4 + r2][col] = f2bf((acc[ct][r2] + bb) * SC);
      }
    }
  }
  asm volatile("s_waitcnt lgkmcnt(0)" ::: "memory");
  __builtin_amdgcn_s_barrier();

  // ---- Phase D: attention; wave w: head h, q rows rbase..rbase+128 (8 subtiles) ----
  {
    const float* bmh = bm + (size_t)(wdw * 4 + h) * 32768;
    float* attnh = attn_out + (size_t)(b * 4 + h) * 32768;
    for (int qt = 0; qt < 8; ++qt) {
      int row16 = rbase + qt * 16;
      s16x8 bq = *(const s16x8*)&qhL[row16 + lm][h * 32 + lg * 8];
      f32x4 S[8];  // S^T: row n2 = ct*16+lg*4+r, col q = lm
#pragma unroll
      for (int ct = 0; ct < 8; ++ct)
        S[ct] = __builtin_amdgcn_mfma_f32_16x16x32_bf16(ak[ct], bq, zero, 0, 0, 0);
      float m = -1e30f;
#pragma unroll
      for (int ct = 0; ct < 8; ++ct) {
        float4 bv = *(const float4*)(bmh + (size_t)(row16 + lm) * 128 + ct * 16 + lg * 4);
        S[ct][0] += bv.x; S[ct][1] += bv.y; S[ct][2] += bv.z; S[ct][3] += bv.w;
        m = fmaxf(m, fmaxf(fmaxf(S[ct][0], S[ct][1]), fmaxf(S[ct][2], S[ct][3])));
      }
      m = fmaxf(m, __shfl_xor(m, 16));
      m = fmaxf(m, __shfl_xor(m, 32));
      float s = 0.f;
#pragma unroll
      for (int ct = 0; ct < 8; ++ct) {
#pragma unroll
        for (int r2 = 0; r2 < 4; ++r2) { S[ct][r2] = __expf(S[ct][r2] - m); s += S[ct][r2]; }
      }
      s += __shfl_xor(s, 16);
      s += __shfl_xor(s, 32);
      float inv = 1.0f / s;
      float* adst = attnh + row16 * 128;
      s16x8 pfrag[4];
#pragma unroll
      for (int ch = 0; ch < 2; ++ch) {
#pragma unroll
        for (int cc = 0; cc < 4; ++cc) {
          int ct = ch * 4 + cc;
          f32x4 pv = { S[ct][0] * inv, S[ct][1] * inv, S[ct][2] * inv, S[ct][3] * inv };
          *(f32x4*)(aSt + lm * 68 + cc * 16 + lg * 4) = pv;
        }
        // NT store: 16 rows x 256B (2 full 128B lines per segment)
#pragma unroll
        for (int i = 0; i < 4; ++i) {
          int o = l * 4 + i * 256;
          int row = o >> 6, col = o & 63;
          f32x4 v = *(const f32x4*)(aSt + row * 68 + col);
          __builtin_nontemporal_store(v, (f32x4*)(adst + row * 128 + ch * 64 + col));
        }
#pragma unroll
        for (int k2 = 0; k2 < 2; ++k2) {
          const float* pp = aSt + lm * 68 + k2 * 32 + lg * 8;
          pfrag[ch * 2 + k2] = cvt8(*(const f32x4*)pp, *(const f32x4*)(pp + 4));
        }
      }
      f32x4 O[2];
      O[0] = zero; O[1] = zero;
#pragma unroll
      for (int kk = 0; kk < 4; ++kk)
#pragma unroll
        for (int cd = 0; cd < 2; ++cd)
          O[cd] = __builtin_amdgcn_mfma_f32_16x16x32_bf16(av[kk * 2 + cd], pfrag[kk], O[cd], 0, 0, 0);
      // X overlay: write into qhL cells of this (row-range, head band) — same-wave safe
#pragma unroll
      for (int cd = 0; cd < 2; ++cd) {
        s16x4 pk;
#pragma unroll
        for (int r2 = 0; r2 < 4; ++r2) pk[r2] = (short)f2bf(O[cd][r2]);
        *(s16x4*)&qhL[row16 + lm][h * 32 + cd * 16 + lg * 4] = pk;
      }
    }
  }
  asm volatile("s_waitcnt lgkmcnt(0)" ::: "memory");
  __builtin_amdgcn_s_barrier();

  // ---- Phase E: out-proj; wave w -> rows w*32..+32 ----
  {
#pragma unroll
    for (int it = 0; it < 2; ++it) {
      int r0 = w * 32 + it * 16;
      f32x4 acc[8];
#pragma unroll
      for (int i = 0; i < 8; ++i) acc[i] = zero;
#pragma unroll
      for (int kk = 0; kk < 4; ++kk) {
        s16x8 a = *(const s16x8*)&qhL[r0 + lm][kk * 32 + lg * 8];
#pragma unroll
        for (int ct = 0; ct < 8; ++ct) {
          s16x8 bf = *(const s16x8*)(pwb + (ct * 16 + lm) * 128 + kk * 32 + lg * 8);
          acc[ct] = __builtin_amdgcn_mfma_f32_16x16x32_bf16(a, bf, acc[ct], 0, 0, 0);
        }
      }
#pragma unroll
      for (int ct = 0; ct < 8; ++ct) {
        int col = ct * 16 + lm;
        float bb = pb[col];
#pragma unroll
        for (int r2 = 0; r2 < 4; ++r2) acc[ct][r2] += bb;
      }
      float* xdst = xout + ((size_t)b * 256 + r0) * 128;
#pragma unroll
      for (int ch = 0; ch < 2; ++ch) {
#pragma unroll
        for (int cc = 0; cc < 4; ++cc) {
          int ct = ch * 4 + cc;
#pragma unroll
          for (int r2 = 0; r2 < 4; ++r2)
            aSt[(lg * 4 + r2) * 68 + cc * 16 + lm] = acc[ct][r2];
        }
#pragma unroll
        for (int i = 0; i < 4; ++i) {
          int o = l * 4 + i * 256;
          int row = o >> 6, col = o & 63;
          f32x4 v = *(const f32x4*)(aSt + row * 68 + col);
          __builtin_nontemporal_store(v, (f32x4*)(xdst + row * 128 + ch * 64 + col));
        }
      }
    }
  }
}

extern "C" void kernel_launch(void* const* d_in, const int* in_sizes, int n_in,
                              void* d_out, int out_size, void* d_ws, size_t ws_size,
                              hipStream_t stream) {
  const float* q    = (const float*)d_in[0];
  const float* kv   = (const float*)d_in[1];
  const float* mask = (const float*)d_in[2];
  const float* qw   = (const float*)d_in[3];
  const float* qb   = (const float*)d_in[4];
  const float* kvw  = (const float*)d_in[5];
  const float* kvb  = (const float*)d_in[6];
  const float* pw   = (const float*)d_in[7];
  const float* pb   = (const float*)d_in[8];
  const float* rpb  = (const float*)d_in[9];
  const int* relidx = (const int*)d_in[10];

  float* xout = (float*)d_out;
  float* attn = xout + (size_t)1024 * 256 * 128;   // 33,554,432

  char* ws = (char*)d_ws;
  unsigned short* qwb  = (unsigned short*)ws;                 // 32 KB
  unsigned short* kvwb = (unsigned short*)(ws + 32768);       // 64 KB
  unsigned short* pwb  = (unsigned short*)(ws + 98304);       // 32 KB
  float*          bm   = (float*)(ws + 131072);               // 32 MB

  kw_prep<<<2048, 256, 0, stream>>>(qw, kvw, pw, rpb, relidx, mask, qwb, kvwb, pwb, bm);
  kmega<<<1024, 512, 0, stream>>>(q, kv, qwb, qb, kvwb, kvb, bm, pwb, pb, attn, xout);
}

// Round 19
// 335.664 us; speedup vs baseline: 1.5642x; 1.0108x over previous
//
#include <hip/hip_runtime.h>

// WindowAttention3D: B=1024, N1=256, N2=128, C=128, NH=4, hd=32, nW=64
// out = [x (1024*256*128 f32)] ++ [attn (1024*4*256*128 f32)]
// R19: R17 mega-fusion (339us, passed) + two zero-risk phase-D tweaks:
//      (1) bm register double-buffer prefetch (R12-proven body() pattern),
//      (2) s_setprio(1) around phase-D MFMA clusters (waves drift in D).
//      qhL overlay ordering identical to R17 (strictly serial per qt).

typedef __attribute__((ext_vector_type(8))) short s16x8;
typedef __attribute__((ext_vector_type(4))) short s16x4;
typedef __attribute__((ext_vector_type(4))) float f32x4;

static __device__ __forceinline__ unsigned short f2bf(float f) {
  union { float f; unsigned u; } v; v.f = f;
  unsigned r = v.u + 0x7FFFu + ((v.u >> 16) & 1u);
  return (unsigned short)(r >> 16);
}

static __device__ __forceinline__ s16x8 cvt8(f32x4 a0, f32x4 a1) {
  s16x8 r;
  r[0] = (short)f2bf(a0[0]); r[1] = (short)f2bf(a0[1]);
  r[2] = (short)f2bf(a0[2]); r[3] = (short)f2bf(a0[3]);
  r[4] = (short)f2bf(a1[0]); r[5] = (short)f2bf(a1[1]);
  r[6] = (short)f2bf(a1[2]); r[7] = (short)f2bf(a1[3]);
  return r;
}

// ---------------- prep: weights->bf16, combined bias+mask table ----------------
// bm[w][h][q][n2] = rpb[rel_index[q][n2]][h] + mask[w][q][n2]   (f32, 32 MB)
__global__ void kw_prep(const float* __restrict__ qw, const float* __restrict__ kvw,
                        const float* __restrict__ pw, const float* __restrict__ rpb,
                        const int* __restrict__ relidx, const float* __restrict__ mask,
                        unsigned short* __restrict__ qwb, unsigned short* __restrict__ kvwb,
                        unsigned short* __restrict__ pwb, float* __restrict__ bm) {
  int tid = blockIdx.x * 256 + threadIdx.x;
  int stride = gridDim.x * 256;
  for (int i = tid; i < 65536; i += stride) {
    if (i < 16384)      qwb[i] = f2bf(qw[i]);
    else if (i < 49152) kvwb[i - 16384] = f2bf(kvw[i - 16384]);
    else                pwb[i - 49152] = f2bf(pw[i - 49152]);
  }
  for (int i = tid; i < 2097152; i += stride) {
    int wdw = i >> 15, j = i & 32767;
    int rel = relidx[j];
    float4 tv = *(const float4*)(rpb + rel * 4);
    float mk = mask[i];
    float* d = bm + (size_t)(wdw * 4) * 32768 + j;
    d[0]      = tv.x + mk;
    d[32768]  = tv.y + mk;
    d[65536]  = tv.z + mk;
    d[98304]  = tv.w + mk;
  }
}

// ---------------- mega: kv-proj + q-proj + attention + out-proj per b ----------------
__global__ __launch_bounds__(512) void kmega(const float* __restrict__ q,
    const float* __restrict__ kv, const unsigned short* __restrict__ qwb,
    const float* __restrict__ qb, const unsigned short* __restrict__ kvwb,
    const float* __restrict__ kvb, const float* __restrict__ bm,
    const unsigned short* __restrict__ pwb, const float* __restrict__ pb,
    float* __restrict__ attn_out, float* __restrict__ xout) {
  __shared__ unsigned short big[256 * 136];   // kL[128][136]+vL[128][136] / qhL-X[256][136]
  __shared__ float scratch[8][1088] __attribute__((aligned(16))); // per-wave [16][68] f32
  unsigned short (*kL)[136]  = (unsigned short(*)[136])big;              // [128][136]
  unsigned short (*vL)[136]  = (unsigned short(*)[136])(big + 128 * 136);// [128][136]
  unsigned short (*qhL)[136] = (unsigned short(*)[136])big;              // [256][136] overlay

  int b = blockIdx.x;
  int wdw = b & 63;
  int t = threadIdx.x;
  int w = t >> 6, l = t & 63, lm = l & 15, lg = l >> 4;
  float* aSt = scratch[w];
  const f32x4 zero = {0.f, 0.f, 0.f, 0.f};

  // ---- Phase A: kv-proj into LDS; wave w -> kv rows w*16..+16, all 256 cols ----
  {
    const float* arow = kv + (size_t)(b * 128 + w * 16 + lm) * 128;
    f32x4 acc[16];
#pragma unroll
    for (int i = 0; i < 16; ++i) acc[i] = zero;
#pragma unroll
    for (int kk = 0; kk < 4; ++kk) {
      f32x4 a0 = __builtin_nontemporal_load((const f32x4*)(arow + kk * 32 + lg * 8));
      f32x4 a1 = __builtin_nontemporal_load((const f32x4*)(arow + kk * 32 + lg * 8 + 4));
      s16x8 a = cvt8(a0, a1);
#pragma unroll
      for (int ct = 0; ct < 16; ++ct) {
        s16x8 bf = *(const s16x8*)(kvwb + (ct * 16 + lm) * 128 + kk * 32 + lg * 8);
        acc[ct] = __builtin_amdgcn_mfma_f32_16x16x32_bf16(a, bf, acc[ct], 0, 0, 0);
      }
    }
#pragma unroll
    for (int ct = 0; ct < 16; ++ct) {
      int col = ct * 16 + lm;
      float bb = kvb[col];
      if (ct < 8) {               // K -> kL[n2][col]
#pragma unroll
        for (int r = 0; r < 4; ++r)
          kL[w * 16 + lg * 4 + r][col] = f2bf(acc[ct][r] + bb);
      } else {                    // V -> vL[d][n2] (transposed)
        int d = col - 128;
        s16x4 pk;
#pragma unroll
        for (int r = 0; r < 4; ++r) pk[r] = (short)f2bf(acc[ct][r] + bb);
        *(s16x4*)&vL[d][w * 16 + lg * 4] = pk;
      }
    }
  }
  asm volatile("s_waitcnt lgkmcnt(0)" ::: "memory");
  __builtin_amdgcn_s_barrier();

  // ---- Phase B: per-wave head K/V into registers (wave w: head h, q-half) ----
  int h = w & 3, rbase = (w >> 2) * 128;
  s16x8 ak[8], av[8];
#pragma unroll
  for (int ct = 0; ct < 8; ++ct)
    ak[ct] = *(const s16x8*)&kL[ct * 16 + lm][h * 32 + lg * 8];
#pragma unroll
  for (int kk = 0; kk < 4; ++kk)
#pragma unroll
    for (int cd = 0; cd < 2; ++cd)
      av[kk * 2 + cd] = *(const s16x8*)&vL[h * 32 + cd * 16 + lm][kk * 32 + lg * 8];
  asm volatile("s_waitcnt lgkmcnt(0)" ::: "memory");
  __builtin_amdgcn_s_barrier();   // K/V now in registers; LDS free for qh overlay

  // ---- Phase C: q-proj into qhL (overlay); wave w -> rows w*32..+32 ----
  {
    const float SC = 0.17677669529663687f;   // 32^-0.5
#pragma unroll
    for (int it = 0; it < 2; ++it) {
      int r0 = w * 32 + it * 16;
      const float* arow = q + (size_t)(b * 256 + r0 + lm) * 128;
      f32x4 acc[8];
#pragma unroll
      for (int i = 0; i < 8; ++i) acc[i] = zero;
#pragma unroll
      for (int kk = 0; kk < 4; ++kk) {
        f32x4 a0 = __builtin_nontemporal_load((const f32x4*)(arow + kk * 32 + lg * 8));
        f32x4 a1 = __builtin_nontemporal_load((const f32x4*)(arow + kk * 32 + lg * 8 + 4));
        s16x8 a = cvt8(a0, a1);
#pragma unroll
        for (int ct = 0; ct < 8; ++ct) {
          s16x8 bf = *(const s16x8*)(qwb + (ct * 16 + lm) * 128 + kk * 32 + lg * 8);
          acc[ct] = __builtin_amdgcn_mfma_f32_16x16x32_bf16(a, bf, acc[ct], 0, 0, 0);
        }
      }
#pragma unroll
      for (int ct = 0; ct < 8; ++ct) {
        int col = ct * 16 + lm;
        float bb = qb[col];
#pragma unroll
        for (int r2 = 0; r2 < 4; ++r2)
          qhL[r0 + lg * 4 + r2][col] = f2bf((acc[ct][r2] + bb) * SC);
      }
    }
  }
  asm volatile("s_waitcnt lgkmcnt(0)" ::: "memory");
  __builtin_amdgcn_s_barrier();

  // ---- Phase D: attention; serial per qt (R17 order), bm double-buffer prefetch ----
  {
    const float* bmh = bm + (size_t)(wdw * 4 + h) * 32768;
    float* attnh = attn_out + (size_t)(b * 4 + h) * 32768;

    f32x4 bmA[8], bmB[8];
#pragma unroll
    for (int ct = 0; ct < 8; ++ct)
      bmA[ct] = *(const f32x4*)(bmh + (size_t)(rbase + lm) * 128 + ct * 16 + lg * 4);

    // Full serial body for one 16-row subtile (identical ordering to R17).
    auto body = [&](int row16, f32x4* bmc, f32x4* bmn, bool pre) {
      s16x8 bq = *(const s16x8*)&qhL[row16 + lm][h * 32 + lg * 8];
      f32x4 S[8];  // S^T: row n2 = ct*16+lg*4+r, col q = lm
      __builtin_amdgcn_s_setprio(1);
#pragma unroll
      for (int ct = 0; ct < 8; ++ct)
        S[ct] = __builtin_amdgcn_mfma_f32_16x16x32_bf16(ak[ct], bq, zero, 0, 0, 0);
      __builtin_amdgcn_s_setprio(0);
      if (pre) {   // issue next tile's bm loads; latency hides under softmax+PV
#pragma unroll
        for (int ct = 0; ct < 8; ++ct)
          bmn[ct] = *(const f32x4*)(bmh + (size_t)(row16 + 16 + lm) * 128 + ct * 16 + lg * 4);
      }
      float m = -1e30f;
#pragma unroll
      for (int ct = 0; ct < 8; ++ct) {
        S[ct][0] += bmc[ct][0]; S[ct][1] += bmc[ct][1];
        S[ct][2] += bmc[ct][2]; S[ct][3] += bmc[ct][3];
        m = fmaxf(m, fmaxf(fmaxf(S[ct][0], S[ct][1]), fmaxf(S[ct][2], S[ct][3])));
      }
      m = fmaxf(m, __shfl_xor(m, 16));
      m = fmaxf(m, __shfl_xor(m, 32));
      float s = 0.f;
#pragma unroll
      for (int ct = 0; ct < 8; ++ct) {
#pragma unroll
        for (int r2 = 0; r2 < 4; ++r2) { S[ct][r2] = __expf(S[ct][r2] - m); s += S[ct][r2]; }
      }
      s += __shfl_xor(s, 16);
      s += __shfl_xor(s, 32);
      float inv = 1.0f / s;
      float* adst = attnh + row16 * 128;
      s16x8 pfrag[4];
#pragma unroll
      for (int ch = 0; ch < 2; ++ch) {
#pragma unroll
        for (int cc = 0; cc < 4; ++cc) {
          int ct = ch * 4 + cc;
          f32x4 pv = { S[ct][0] * inv, S[ct][1] * inv, S[ct][2] * inv, S[ct][3] * inv };
          *(f32x4*)(aSt + lm * 68 + cc * 16 + lg * 4) = pv;
        }
        // NT store: 16 rows x 256B (2 full 128B lines per segment)
#pragma unroll
        for (int i = 0; i < 4; ++i) {
          int o = l * 4 + i * 256;
          int row = o >> 6, col = o & 63;
          f32x4 v = *(const f32x4*)(aSt + row * 68 + col);
          __builtin_nontemporal_store(v, (f32x4*)(adst + row * 128 + ch * 64 + col));
        }
#pragma unroll
        for (int k2 = 0; k2 < 2; ++k2) {
          const float* pp = aSt + lm * 68 + k2 * 32 + lg * 8;
          pfrag[ch * 2 + k2] = cvt8(*(const f32x4*)pp, *(const f32x4*)(pp + 4));
        }
      }
      f32x4 O[2];
      O[0] = zero; O[1] = zero;
      __builtin_amdgcn_s_setprio(1);
#pragma unroll
      for (int kk = 0; kk < 4; ++kk)
#pragma unroll
        for (int cd = 0; cd < 2; ++cd)
          O[cd] = __builtin_amdgcn_mfma_f32_16x16x32_bf16(av[kk * 2 + cd], pfrag[kk], O[cd], 0, 0, 0);
      __builtin_amdgcn_s_setprio(0);
      // X overlay into qhL (same row16 this wave just consumed) — same-wave safe
#pragma unroll
      for (int cd = 0; cd < 2; ++cd) {
        s16x4 pk;
#pragma unroll
        for (int r2 = 0; r2 < 4; ++r2) pk[r2] = (short)f2bf(O[cd][r2]);
        *(s16x4*)&qhL[row16 + lm][h * 32 + cd * 16 + lg * 4] = pk;
      }
    };

    body(rbase +   0, bmA, bmB, true);
    body(rbase +  16, bmB, bmA, true);
    body(rbase +  32, bmA, bmB, true);
    body(rbase +  48, bmB, bmA, true);
    body(rbase +  64, bmA, bmB, true);
    body(rbase +  80, bmB, bmA, true);
    body(rbase +  96, bmA, bmB, true);
    body(rbase + 112, bmB, bmA, false);
  }
  asm volatile("s_waitcnt lgkmcnt(0)" ::: "memory");
  __builtin_amdgcn_s_barrier();

  // ---- Phase E: out-proj; wave w -> rows w*32..+32 ----
  {
#pragma unroll
    for (int it = 0; it < 2; ++it) {
      int r0 = w * 32 + it * 16;
      f32x4 acc[8];
#pragma unroll
      for (int i = 0; i < 8; ++i) acc[i] = zero;
#pragma unroll
      for (int kk = 0; kk < 4; ++kk) {
        s16x8 a = *(const s16x8*)&qhL[r0 + lm][kk * 32 + lg * 8];
#pragma unroll
        for (int ct = 0; ct < 8; ++ct) {
          s16x8 bf = *(const s16x8*)(pwb + (ct * 16 + lm) * 128 + kk * 32 + lg * 8);
          acc[ct] = __builtin_amdgcn_mfma_f32_16x16x32_bf16(a, bf, acc[ct], 0, 0, 0);
        }
      }
#pragma unroll
      for (int ct = 0; ct < 8; ++ct) {
        int col = ct * 16 + lm;
        float bb = pb[col];
#pragma unroll
        for (int r2 = 0; r2 < 4; ++r2) acc[ct][r2] += bb;
      }
      float* xdst = xout + ((size_t)b * 256 + r0) * 128;
#pragma unroll
      for (int ch = 0; ch < 2; ++ch) {
#pragma unroll
        for (int cc = 0; cc < 4; ++cc) {
          int ct = ch * 4 + cc;
#pragma unroll
          for (int r2 = 0; r2 < 4; ++r2)
            aSt[(lg * 4 + r2) * 68 + cc * 16 + lm] = acc[ct][r2];
        }
#pragma unroll
        for (int i = 0; i < 4; ++i) {
          int o = l * 4 + i * 256;
          int row = o >> 6, col = o & 63;
          f32x4 v = *(const f32x4*)(aSt + row * 68 + col);
          __builtin_nontemporal_store(v, (f32x4*)(xdst + row * 128 + ch * 64 + col));
        }
      }
    }
  }
}

extern "C" void kernel_launch(void* const* d_in, const int* in_sizes, int n_in,
                              void* d_out, int out_size, void* d_ws, size_t ws_size,
                              hipStream_t stream) {
  const float* q    = (const float*)d_in[0];
  const float* kv   = (const float*)d_in[1];
  const float* mask = (const float*)d_in[2];
  const float* qw   = (const float*)d_in[3];
  const float* qb   = (const float*)d_in[4];
  const float* kvw  = (const float*)d_in[5];
  const float* kvb  = (const float*)d_in[6];
  const float* pw   = (const float*)d_in[7];
  const float* pb   = (const float*)d_in[8];
  const float* rpb  = (const float*)d_in[9];
  const int* relidx = (const int*)d_in[10];

  float* xout = (float*)d_out;
  float* attn = xout + (size_t)1024 * 256 * 128;   // 33,554,432

  char* ws = (char*)d_ws;
  unsigned short* qwb  = (unsigned short*)ws;                 // 32 KB
  unsigned short* kvwb = (unsigned short*)(ws + 32768);       // 64 KB
  unsigned short* pwb  = (unsigned short*)(ws + 98304);       // 32 KB
  float*          bm   = (float*)(ws + 131072);               // 32 MB

  kw_prep<<<2048, 256, 0, stream>>>(qw, kvw, pw, rpb, relidx, mask, qwb, kvwb, pwb, bm);
  kmega<<<1024, 512, 0, stream>>>(q, kv, qwb, qb, kvwb, kvb, bm, pwb, pb, attn, xout);
}